// Round 5
// baseline (32.697 us; speedup 1.0000x reference)
//
#include <hip/hip_runtime.h>
#include <math.h>

#define NEXP 16
#define BLOCK 256
#define K 2   // tokens per thread; x[2][16]=32 VGPR keeps total <=64 (8 waves/SIMD)

__global__ __launch_bounds__(BLOCK) void sparsemixer_kernel(
    const float* __restrict__ logits, float* __restrict__ out, int n_tok) {
    int base = blockIdx.x * (BLOCK * K) + threadIdx.x;

    // Issue ALL loads first: 2 rows x 4 float4 = 8 outstanding dwordx4 / lane.
    float x[K][NEXP];
    const float4* rows = reinterpret_cast<const float4*>(logits);
#pragma unroll
    for (int k = 0; k < K; ++k) {
        int t = base + k * BLOCK;
        if (t < n_tok) {
            const float4* row = rows + (size_t)t * 4;
#pragma unroll
            for (int q = 0; q < 4; ++q) {
                float4 v = row[q];
                x[k][4 * q + 0] = v.x;
                x[k][4 * q + 1] = v.y;
                x[k][4 * q + 2] = v.z;
                x[k][4 * q + 3] = v.w;
            }
        }
    }

    float2* oidx = reinterpret_cast<float2*>(out);
    float2* oval = reinterpret_cast<float2*>(out) + n_tok;

#pragma unroll
    for (int k = 0; k < K; ++k) {
        int t = base + k * BLOCK;
        if (t >= n_tok) continue;

        // Single-scan top-2, first-index tie semantics (strict >).
        float m0 = x[k][0], m1 = -INFINITY;
        int mi0 = 0, mi1 = 0;
#pragma unroll
        for (int j = 1; j < NEXP; ++j) {
            float v = x[k][j];
            if (v > m0) { m1 = m0; mi1 = mi0; m0 = v; mi0 = j; }
            else if (v > m1) { m1 = v; mi1 = j; }
        }

        // Shared-exp masked softmax denominators (see R4):
        //   e_j = exp(x_j - m0); v0 = 1/sum0; v1 = exp(m1-m0)/ (sum1_shifted)
        // Mask test bit-identical to R2/R4:
        //   masked = (m - v) > 0.02f * fmax(|v|, m)
        // mi0's pass-1 contribution is exactly exp(0)=1 -> subtract 1.0 once.
        float s0a = 0.f, s0b = 0.f, s1a = 0.f, s1b = 0.f;
#pragma unroll
        for (int j = 0; j < NEXP; ++j) {
            float v = x[k][j];
            float ev = __expf(v - m0);
            float d0 = fmaxf(fabsf(v), m0);
            bool masked0 = (m0 - v) > 0.02f * d0;
            float d1 = fmaxf(fabsf(v), m1);
            bool masked1 = (m1 - v) > 0.02f * d1;
            if (j & 1) {
                s0b += masked0 ? 0.f : ev;
                s1b += masked1 ? 0.f : ev;
            } else {
                s0a += masked0 ? 0.f : ev;
                s1a += masked1 ? 0.f : ev;
            }
        }
        float sum0 = s0a + s0b;
        float sum1 = (s1a + s1b) - 1.0f;
        float v0 = __builtin_amdgcn_rcpf(sum0);
        float v1 = __expf(m1 - m0) * __builtin_amdgcn_rcpf(sum1);

        oidx[t] = make_float2((float)mi0, (float)mi1);
        oval[t] = make_float2(v0, v1);
    }
}

extern "C" void kernel_launch(void* const* d_in, const int* in_sizes, int n_in,
                              void* d_out, int out_size, void* d_ws, size_t ws_size,
                              hipStream_t stream) {
    const float* logits = (const float*)d_in[0];
    float* out = (float*)d_out;
    int n_tok = in_sizes[0] / NEXP;
    int per_block = BLOCK * K;
    int grid = (n_tok + per_block - 1) / per_block;
    sparsemixer_kernel<<<grid, BLOCK, 0, stream>>>(logits, out, n_tok);
}

// Round 6
// 29.765 us; speedup vs baseline: 1.0985x; 1.0985x over previous
//
#include <hip/hip_runtime.h>
#include <math.h>

#define NEXP 16
#define BLOCK 256

__global__ __launch_bounds__(BLOCK) void sparsemixer_kernel(
    const float* __restrict__ logits, float* __restrict__ out, int n_tok) {
    int t = blockIdx.x * BLOCK + threadIdx.x;
    if (t >= n_tok) return;

    // Load the 16-logit row into registers (4 x float4 = 64B per lane, coalesced).
    float x[NEXP];
    const float4* row = reinterpret_cast<const float4*>(logits + (size_t)t * NEXP);
#pragma unroll
    for (int q = 0; q < 4; ++q) {
        float4 v = row[q];
        x[4 * q + 0] = v.x;
        x[4 * q + 1] = v.y;
        x[4 * q + 2] = v.z;
        x[4 * q + 3] = v.w;
    }

    // Single-scan top-2 with first-index tie semantics (strict >).
    float m0 = x[0], m1 = -INFINITY;
    int mi0 = 0, mi1 = 0;
#pragma unroll
    for (int j = 1; j < NEXP; ++j) {
        float v = x[j];
        if (v > m0) { m1 = m0; mi1 = mi0; m0 = v; mi0 = j; }
        else if (v > m1) { m1 = v; mi1 = j; }
    }

    // Shared-exp masked softmax denominators (R4 structure):
    //   e_j = exp(x_j - m0); v0 = 1/sum0; v1 = exp(m1-m0)/sum1_shifted.
    //   mi0's stream-1 term is exactly exp(0)=1 -> subtract 1.0 once.
    //
    // FAST PATH (m1 >= 0 => m0 >= 0): the reference mask test
    //   (m - v) > 0.02*fmax(|v|, m)
    // is bit-equivalent to (m - v) > fl(0.02*m) for every v:
    //   |v| <= m  -> den == m, literally same expression;
    //   |v| >  m  (v<0) -> both forms provably masked in fp
    //     (fl(m+|v|) >= |v| > fl(0.02*|v|) and >= |v| > m >= fl(0.02*m)).
    // Rows with m1 < 0 (~2.6e-4 of tokens) take the exact R4 form.
    float s0a = 0.f, s0b = 0.f, s1a = 0.f, s1b = 0.f;
    if (m1 >= 0.0f) {
        float th0 = 0.02f * m0;
        float th1 = 0.02f * m1;
#pragma unroll
        for (int j = 0; j < NEXP; ++j) {
            float v = x[j];
            float ev = __expf(v - m0);
            bool masked0 = (m0 - v) > th0;
            bool masked1 = (m1 - v) > th1;
            if (j & 1) {
                s0b += masked0 ? 0.f : ev;
                s1b += masked1 ? 0.f : ev;
            } else {
                s0a += masked0 ? 0.f : ev;
                s1a += masked1 ? 0.f : ev;
            }
        }
    } else {
#pragma unroll
        for (int j = 0; j < NEXP; ++j) {
            float v = x[j];
            float ev = __expf(v - m0);
            float d0 = fmaxf(fabsf(v), m0);
            bool masked0 = (m0 - v) > 0.02f * d0;
            float d1 = fmaxf(fabsf(v), m1);
            bool masked1 = (m1 - v) > 0.02f * d1;
            if (j & 1) {
                s0b += masked0 ? 0.f : ev;
                s1b += masked1 ? 0.f : ev;
            } else {
                s0a += masked0 ? 0.f : ev;
                s1a += masked1 ? 0.f : ev;
            }
        }
    }
    float sum0 = s0a + s0b;
    float sum1 = (s1a + s1b) - 1.0f;   // remove the mi0 term (exactly 1.0)
    float v0 = __builtin_amdgcn_rcpf(sum0);
    float v1 = __expf(m1 - m0) * __builtin_amdgcn_rcpf(sum1);

    // Outputs: [N,2] indices (as float), then [N,2] values.
    float2* oidx = reinterpret_cast<float2*>(out);
    float2* oval = reinterpret_cast<float2*>(out) + n_tok;
    oidx[t] = make_float2((float)mi0, (float)mi1);
    oval[t] = make_float2(v0, v1);
}

extern "C" void kernel_launch(void* const* d_in, const int* in_sizes, int n_in,
                              void* d_out, int out_size, void* d_ws, size_t ws_size,
                              hipStream_t stream) {
    const float* logits = (const float*)d_in[0];
    float* out = (float*)d_out;
    int n_tok = in_sizes[0] / NEXP;
    int grid = (n_tok + BLOCK - 1) / BLOCK;
    sparsemixer_kernel<<<grid, BLOCK, 0, stream>>>(logits, out, n_tok);
}